// Round 1
// baseline (1315.101 us; speedup 1.0000x reference)
//
#include <hip/hip_runtime.h>
#include <cstdint>
#include <cstddef>

#define N_ANCH   120000
#define K_PRE    2000
#define K_POST   512
#define CAP      4096
#define IOU_THR  0.7f
#define IMGF     800.0f
#define CLIPV    4.135166556742356f
#define FH       200
#define FW       200
#define FC       256
#define SCALE    0.25f

struct Ws {
    uint32_t T;          // threshold key (2000th largest)
    uint32_t cnt;        // gather counter
    int32_t  nk;         // number kept after NMS
    uint32_t pad;
    unsigned long long combo[CAP];   // (~key)<<32 | index, sorted ascending
    float4   cand[K_PRE];            // decoded candidate boxes, score-desc order
    int      rows[K_POST];           // candidate rank per output row, -1 = invalid
};

// Monotonic float -> uint key (larger float => larger uint). No NaNs expected.
__device__ inline uint32_t fkey(float f) {
    uint32_t u = __float_as_uint(f);
    return (u & 0x80000000u) ? ~u : (u | 0x80000000u);
}

// ---------------------------------------------------------------------------
// Kernel 1: single-block 4-pass radix select: exact key of the 2000th-largest
// objectness. Wave-privatized histograms to cut LDS atomic contention.
// ---------------------------------------------------------------------------
__global__ __launch_bounds__(1024) void radix_select_k(const float* __restrict__ obj,
                                                       Ws* __restrict__ ws) {
    __shared__ uint32_t hist[16][256];
    __shared__ uint32_t s_prefix;
    __shared__ int s_k;
    const int tid = threadIdx.x;
    const int wave = tid >> 6;
    if (tid == 0) { s_prefix = 0u; s_k = K_PRE; }
    __syncthreads();
    for (int b = 3; b >= 0; --b) {
        for (int i = tid; i < 16 * 256; i += 1024) ((uint32_t*)hist)[i] = 0u;
        __syncthreads();
        const uint32_t prefix = s_prefix;
        const uint32_t maskHigh = (b == 3) ? 0u : (0xFFFFFFFFu << (8 * (b + 1)));
        for (int i = tid; i < N_ANCH; i += 1024) {
            uint32_t u = fkey(obj[i]);
            if ((u & maskHigh) == prefix)
                atomicAdd(&hist[wave][(u >> (8 * b)) & 0xFFu], 1u);
        }
        __syncthreads();
        if (tid < 256) {
            uint32_t s = 0;
            for (int w = 0; w < 16; ++w) s += hist[w][tid];
            hist[0][tid] = s;
        }
        __syncthreads();
        if (tid == 0) {
            uint32_t cum = 0;
            int v = 255;
            for (; v > 0; --v) {
                uint32_t h = hist[0][v];
                if (cum + h >= (uint32_t)s_k) break;
                cum += h;
            }
            s_prefix = prefix | ((uint32_t)v << (8 * b));
            s_k -= (int)cum;
        }
        __syncthreads();
    }
    if (tid == 0) { ws->T = s_prefix; ws->cnt = 0u; ws->nk = 0; }
}

// ---------------------------------------------------------------------------
// Kernel 2: grid-wide gather of all elements with key >= T.
// ---------------------------------------------------------------------------
__global__ void gather_k(const float* __restrict__ obj, Ws* __restrict__ ws) {
    int i = blockIdx.x * blockDim.x + threadIdx.x;
    if (i >= N_ANCH) return;
    const uint32_t T = ws->T;
    uint32_t u = fkey(obj[i]);
    if (u >= T) {
        uint32_t pos = atomicAdd(&ws->cnt, 1u);
        if (pos < CAP)
            ws->combo[pos] = ((unsigned long long)(~u) << 32) | (uint32_t)i;
    }
}

// ---------------------------------------------------------------------------
// Kernel 3: single-block bitonic sort of <=4096 combos (ascending =>
// score desc, index asc — exact lax.top_k order), then decode top-2000 boxes.
// ---------------------------------------------------------------------------
__global__ __launch_bounds__(1024) void sort_decode_k(const float* __restrict__ deltas,
                                                      const float* __restrict__ anchors,
                                                      Ws* __restrict__ ws) {
    __shared__ unsigned long long buf[CAP];
    const int tid = threadIdx.x;
    uint32_t M = ws->cnt;
    if (M > CAP) M = CAP;
    for (int i = tid; i < CAP; i += 1024)
        buf[i] = (i < (int)M) ? ws->combo[i] : 0xFFFFFFFFFFFFFFFFull;
    __syncthreads();
    for (int k = 2; k <= CAP; k <<= 1) {
        for (int j = k >> 1; j > 0; j >>= 1) {
            for (int i = tid; i < CAP; i += 1024) {
                int ixj = i ^ j;
                if (ixj > i) {
                    bool up = ((i & k) == 0);
                    unsigned long long a = buf[i], b = buf[ixj];
                    if ((a > b) == up) { buf[i] = b; buf[ixj] = a; }
                }
            }
            __syncthreads();
        }
    }
    for (int r = tid; r < K_PRE; r += 1024) {
        uint32_t idx = (uint32_t)(buf[r] & 0xFFFFFFFFull);
        float a0 = anchors[idx * 4 + 0], a1 = anchors[idx * 4 + 1];
        float a2 = anchors[idx * 4 + 2], a3 = anchors[idx * 4 + 3];
        float d0 = deltas[idx * 4 + 0],  d1 = deltas[idx * 4 + 1];
        float d2 = fminf(deltas[idx * 4 + 2], CLIPV);
        float d3 = fminf(deltas[idx * 4 + 3], CLIPV);
        float w = a2 - a0, h = a3 - a1;
        float cx = a0 + 0.5f * w, cy = a1 + 0.5f * h;
        float pcx = d0 * w + cx, pcy = d1 * h + cy;
        float pw = expf(d2) * w, ph = expf(d3) * h;
        float x1 = fminf(fmaxf(pcx - 0.5f * pw, 0.0f), IMGF);
        float y1 = fminf(fmaxf(pcy - 0.5f * ph, 0.0f), IMGF);
        float x2 = fminf(fmaxf(pcx + 0.5f * pw, 0.0f), IMGF);
        float y2 = fminf(fmaxf(pcy + 0.5f * ph, 0.0f), IMGF);
        ws->cand[r] = make_float4(x1, y1, x2, y2);
    }
}

// ---------------------------------------------------------------------------
// Kernel 4: sequential greedy NMS (exact reference semantics), boxes in LDS.
// Then compact kept indices -> rows[512] (-1 past the kept count: those rows
// are -inf top_k fillers whose output is exactly 0).
// ---------------------------------------------------------------------------
__global__ __launch_bounds__(1024) void nms_k(Ws* __restrict__ ws) {
    __shared__ float bx1[K_PRE], by1[K_PRE], bx2[K_PRE], by2[K_PRE], ar[K_PRE];
    __shared__ unsigned char supp[K_PRE];
    const int tid = threadIdx.x;
    for (int i = tid; i < K_PRE; i += 1024) {
        float4 b = ws->cand[i];
        bx1[i] = b.x; by1[i] = b.y; bx2[i] = b.z; by2[i] = b.w;
        ar[i] = (b.z - b.x) * (b.w - b.y);
        supp[i] = 0;
    }
    __syncthreads();
    for (int i = 0; i < K_PRE - 1; ++i) {
        if (!supp[i]) {
            const float x1 = bx1[i], y1 = by1[i], x2 = bx2[i], y2 = by2[i], a = ar[i];
            for (int j = i + 1 + tid; j < K_PRE; j += 1024) {
                if (supp[j]) continue;
                float xx1 = fmaxf(x1, bx1[j]);
                float yy1 = fmaxf(y1, by1[j]);
                float xx2 = fminf(x2, bx2[j]);
                float yy2 = fminf(y2, by2[j]);
                float ww = fmaxf(xx2 - xx1, 0.0f);
                float hh = fmaxf(yy2 - yy1, 0.0f);
                float inter = ww * hh;
                float iou = inter / (a + ar[j] - inter + 1e-6f);
                if (iou > IOU_THR) supp[j] = 1;
            }
        }
        __syncthreads();
    }
    if (tid == 0) {
        int nk = 0;
        for (int j = 0; j < K_PRE; ++j) {
            if (!supp[j]) {
                if (nk < K_POST) ws->rows[nk] = j;
                ++nk;
            }
        }
        for (int r = (nk < K_POST ? nk : K_POST); r < K_POST; ++r) ws->rows[r] = -1;
        ws->nk = nk;
    }
}

// ---------------------------------------------------------------------------
// Kernel 5: ROIAlign. grid = (49, 512), block = 256: one output element per
// thread (coalesced stores). Invalid rows -> exact zeros.
// ---------------------------------------------------------------------------
__global__ __launch_bounds__(256) void roi_k(const float* __restrict__ feat,
                                             const Ws* __restrict__ ws,
                                             float* __restrict__ out) {
    const int b = blockIdx.y;
    const int o = blockIdx.x * 256 + threadIdx.x;   // 0..12543
    float* orow = out + (size_t)b * (FC * 49);
    const int row = ws->rows[b];
    if (row < 0) { orow[o] = 0.0f; return; }
    const float4 bx = ws->cand[row];
    const float x1 = bx.x * SCALE, y1 = bx.y * SCALE;
    const float x2 = bx.z * SCALE, y2 = bx.w * SCALE;
    const float rw = fmaxf(x2 - x1, 1.0f);
    const float rh = fmaxf(y2 - y1, 1.0f);
    const float stepx = rw / 14.0f;
    const float stepy = rh / 14.0f;
    const int c = o / 49;
    const int p = o % 49;
    const int oy = p / 7, ox = p % 7;
    const float* fc = feat + (size_t)c * (FH * FW);
    float acc = 0.0f;
    for (int sy = 0; sy < 2; ++sy) {
        float yy = y1 + ((float)(2 * oy + sy) + 0.5f) * stepy;
        float y = fminf(fmaxf(yy, 0.0f), (float)(FH - 1));
        float fy0 = floorf(y);
        int iy0 = (int)fy0;
        int iy1 = min(iy0 + 1, FH - 1);
        float ly = y - fy0;
        for (int sx = 0; sx < 2; ++sx) {
            float xx = x1 + ((float)(2 * ox + sx) + 0.5f) * stepx;
            float x = fminf(fmaxf(xx, 0.0f), (float)(FW - 1));
            float fx0 = floorf(x);
            int ix0 = (int)fx0;
            int ix1 = min(ix0 + 1, FW - 1);
            float lx = x - fx0;
            float v00 = fc[iy0 * FW + ix0];
            float v01 = fc[iy0 * FW + ix1];
            float v10 = fc[iy1 * FW + ix0];
            float v11 = fc[iy1 * FW + ix1];
            acc += v00 * (1.0f - ly) * (1.0f - lx)
                 + v01 * (1.0f - ly) * lx
                 + v10 * ly * (1.0f - lx)
                 + v11 * ly * lx;
        }
    }
    orow[o] = acc * 0.25f;
}

extern "C" void kernel_launch(void* const* d_in, const int* in_sizes, int n_in,
                              void* d_out, int out_size, void* d_ws, size_t ws_size,
                              hipStream_t stream) {
    const float* feature    = (const float*)d_in[0];
    const float* objectness = (const float*)d_in[1];
    const float* deltas     = (const float*)d_in[2];
    const float* anchors    = (const float*)d_in[3];
    Ws* ws = (Ws*)d_ws;
    float* out = (float*)d_out;

    hipLaunchKernelGGL(radix_select_k, dim3(1), dim3(1024), 0, stream, objectness, ws);
    hipLaunchKernelGGL(gather_k, dim3((N_ANCH + 255) / 256), dim3(256), 0, stream,
                       objectness, ws);
    hipLaunchKernelGGL(sort_decode_k, dim3(1), dim3(1024), 0, stream, deltas, anchors, ws);
    hipLaunchKernelGGL(nms_k, dim3(1), dim3(1024), 0, stream, ws);
    hipLaunchKernelGGL(roi_k, dim3(49, 512), dim3(256), 0, stream, feature, ws, out);
}

// Round 2
// 525.843 us; speedup vs baseline: 2.5009x; 2.5009x over previous
//
#include <hip/hip_runtime.h>
#include <cstdint>
#include <cstddef>

#define N_ANCH   120000
#define K_PRE    2000
#define K_POST   512
#define CAP      4096
#define NWORD    32          // ceil(K_PRE/64)
#define IOU_THR  0.7f
#define IMGF     800.0f
#define CLIPV    4.135166556742356f
#define FH       200
#define FW       200
#define FC       256
#define SCALE    0.25f

struct Ws {
    uint32_t T;          // threshold key (2000th largest)
    uint32_t cnt;        // gather counter
    int32_t  nk;         // number kept after NMS
    uint32_t pad;
    unsigned long long combo[CAP];   // (~key)<<32 | index, sorted ascending
    float4   cand[K_PRE];            // decoded candidate boxes, score-desc order
    int      rows[K_POST];           // candidate rank per output row, -1 = invalid
    unsigned long long mask[(size_t)K_PRE * NWORD];  // IoU>thr & (j>i) bitmask
};

// Monotonic float -> uint key (larger float => larger uint). No NaNs expected.
__device__ inline uint32_t fkey(float f) {
    uint32_t u = __float_as_uint(f);
    return (u & 0x80000000u) ? ~u : (u | 0x80000000u);
}

// ---------------------------------------------------------------------------
// Kernel 1: single-block 4-pass radix select: exact key of the 2000th-largest
// objectness. Wave-privatized histograms to cut LDS atomic contention.
// ---------------------------------------------------------------------------
__global__ __launch_bounds__(1024) void radix_select_k(const float* __restrict__ obj,
                                                       Ws* __restrict__ ws) {
    __shared__ uint32_t hist[16][256];
    __shared__ uint32_t s_prefix;
    __shared__ int s_k;
    const int tid = threadIdx.x;
    const int wave = tid >> 6;
    if (tid == 0) { s_prefix = 0u; s_k = K_PRE; }
    __syncthreads();
    for (int b = 3; b >= 0; --b) {
        for (int i = tid; i < 16 * 256; i += 1024) ((uint32_t*)hist)[i] = 0u;
        __syncthreads();
        const uint32_t prefix = s_prefix;
        const uint32_t maskHigh = (b == 3) ? 0u : (0xFFFFFFFFu << (8 * (b + 1)));
        for (int i = tid; i < N_ANCH; i += 1024) {
            uint32_t u = fkey(obj[i]);
            if ((u & maskHigh) == prefix)
                atomicAdd(&hist[wave][(u >> (8 * b)) & 0xFFu], 1u);
        }
        __syncthreads();
        if (tid < 256) {
            uint32_t s = 0;
            for (int w = 0; w < 16; ++w) s += hist[w][tid];
            hist[0][tid] = s;
        }
        __syncthreads();
        if (tid == 0) {
            uint32_t cum = 0;
            int v = 255;
            for (; v > 0; --v) {
                uint32_t h = hist[0][v];
                if (cum + h >= (uint32_t)s_k) break;
                cum += h;
            }
            s_prefix = prefix | ((uint32_t)v << (8 * b));
            s_k -= (int)cum;
        }
        __syncthreads();
    }
    if (tid == 0) { ws->T = s_prefix; ws->cnt = 0u; ws->nk = 0; }
}

// ---------------------------------------------------------------------------
// Kernel 2: grid-wide gather of all elements with key >= T.
// ---------------------------------------------------------------------------
__global__ void gather_k(const float* __restrict__ obj, Ws* __restrict__ ws) {
    int i = blockIdx.x * blockDim.x + threadIdx.x;
    if (i >= N_ANCH) return;
    const uint32_t T = ws->T;
    uint32_t u = fkey(obj[i]);
    if (u >= T) {
        uint32_t pos = atomicAdd(&ws->cnt, 1u);
        if (pos < CAP)
            ws->combo[pos] = ((unsigned long long)(~u) << 32) | (uint32_t)i;
    }
}

// ---------------------------------------------------------------------------
// Kernel 3: single-block bitonic sort of <=4096 combos (ascending =>
// score desc, index asc — exact lax.top_k order), then decode top-2000 boxes.
// ---------------------------------------------------------------------------
__global__ __launch_bounds__(1024) void sort_decode_k(const float* __restrict__ deltas,
                                                      const float* __restrict__ anchors,
                                                      Ws* __restrict__ ws) {
    __shared__ unsigned long long buf[CAP];
    const int tid = threadIdx.x;
    uint32_t M = ws->cnt;
    if (M > CAP) M = CAP;
    for (int i = tid; i < CAP; i += 1024)
        buf[i] = (i < (int)M) ? ws->combo[i] : 0xFFFFFFFFFFFFFFFFull;
    __syncthreads();
    for (int k = 2; k <= CAP; k <<= 1) {
        for (int j = k >> 1; j > 0; j >>= 1) {
            for (int i = tid; i < CAP; i += 1024) {
                int ixj = i ^ j;
                if (ixj > i) {
                    bool up = ((i & k) == 0);
                    unsigned long long a = buf[i], b = buf[ixj];
                    if ((a > b) == up) { buf[i] = b; buf[ixj] = a; }
                }
            }
            __syncthreads();
        }
    }
    for (int r = tid; r < K_PRE; r += 1024) {
        uint32_t idx = (uint32_t)(buf[r] & 0xFFFFFFFFull);
        float a0 = anchors[idx * 4 + 0], a1 = anchors[idx * 4 + 1];
        float a2 = anchors[idx * 4 + 2], a3 = anchors[idx * 4 + 3];
        float d0 = deltas[idx * 4 + 0],  d1 = deltas[idx * 4 + 1];
        float d2 = fminf(deltas[idx * 4 + 2], CLIPV);
        float d3 = fminf(deltas[idx * 4 + 3], CLIPV);
        float w = a2 - a0, h = a3 - a1;
        float cx = a0 + 0.5f * w, cy = a1 + 0.5f * h;
        float pcx = d0 * w + cx, pcy = d1 * h + cy;
        float pw = expf(d2) * w, ph = expf(d3) * h;
        float x1 = fminf(fmaxf(pcx - 0.5f * pw, 0.0f), IMGF);
        float y1 = fminf(fmaxf(pcy - 0.5f * ph, 0.0f), IMGF);
        float x2 = fminf(fmaxf(pcx + 0.5f * pw, 0.0f), IMGF);
        float y2 = fminf(fmaxf(pcy + 0.5f * ph, 0.0f), IMGF);
        ws->cand[r] = make_float4(x1, y1, x2, y2);
    }
}

// ---------------------------------------------------------------------------
// Kernel 4a: build the pairwise suppression bitmask.
// mask[i][w] bit b set  <=>  j = 64w+b, j > i, j < K_PRE, IoU(i,j) > thr.
// grid = K_PRE blocks x 256 threads (4 waves; wave handles words w, w+4, ...).
// ---------------------------------------------------------------------------
__global__ __launch_bounds__(256) void nms_mask_k(Ws* __restrict__ ws) {
    const int i = blockIdx.x;
    const int lane = threadIdx.x & 63;
    const int wave = threadIdx.x >> 6;
    const float4 bi = ws->cand[i];
    const float ai = (bi.z - bi.x) * (bi.w - bi.y);
    for (int wd = wave; wd < NWORD; wd += 4) {
        int j = wd * 64 + lane;
        bool bit = false;
        if (j < K_PRE && j > i) {
            float4 bj = ws->cand[j];
            float aj = (bj.z - bj.x) * (bj.w - bj.y);
            float xx1 = fmaxf(bi.x, bj.x);
            float yy1 = fmaxf(bi.y, bj.y);
            float xx2 = fminf(bi.z, bj.z);
            float yy2 = fminf(bi.w, bj.w);
            float ww = fmaxf(xx2 - xx1, 0.0f);
            float hh = fmaxf(yy2 - yy1, 0.0f);
            float inter = ww * hh;
            float iou = inter / (ai + aj - inter + 1e-6f);
            bit = iou > IOU_THR;
        }
        unsigned long long bal = __ballot(bit);
        if (lane == 0) ws->mask[(size_t)i * NWORD + wd] = bal;
    }
}

// ---------------------------------------------------------------------------
// Kernel 4b: greedy scan over the bitmask — single wave, no barriers.
// Lane L owns suppression word L (L<32). All lanes redundantly track `cur`,
// the replicated copy of the word currently being tested (mask[i] only has
// bits j>i, so tests for i in [64w,64w+64) read only word w). Serial chain
// per i is pure VALU; mask loads are prefetched in register sub-chunks of 16.
// Then parallel compaction: popcount + wave prefix scan -> rows[512].
// ---------------------------------------------------------------------------
__global__ __launch_bounds__(64) void nms_scan_k(Ws* __restrict__ ws) {
    const int lane = threadIdx.x & 63;
    const bool rl = lane < NWORD;
    const unsigned long long* __restrict__ mask = ws->mask;
    unsigned long long supp = 0ull;
    for (int w = 0; w < NWORD; ++w) {
        const int base = w * 64;
        const int nb = (K_PRE - base < 64) ? (K_PRE - base) : 64;  // 64, last=16
        unsigned long long cur = __shfl(supp, w);
        for (int s = 0; s < nb; s += 16) {
            unsigned long long colw[16], rowm[16];
#pragma unroll
            for (int b = 0; b < 16; ++b) {
                const size_t i = (size_t)(base + s + b);
                colw[b] = mask[i * NWORD + w];                    // wave-uniform
                rowm[b] = rl ? mask[i * NWORD + lane] : 0ull;     // per-lane
            }
#pragma unroll
            for (int b = 0; b < 16; ++b) {
                if (!((cur >> (s + b)) & 1ull)) {
                    cur  |= colw[b];
                    supp |= rowm[b];
                }
            }
        }
    }
    // ---- compaction: kept = ~supp (valid bits only) ----
    unsigned long long valid;
    if (lane < NWORD - 1)       valid = ~0ull;
    else if (lane == NWORD - 1) valid = (1ull << (K_PRE - (NWORD - 1) * 64)) - 1ull; // 16 bits
    else                        valid = 0ull;
    unsigned long long keepw = (~supp) & valid;
    int cnt = __popcll(keepw);
    int incl = cnt;
    for (int off = 1; off < 64; off <<= 1) {
        int t = __shfl_up(incl, off);
        if (lane >= off) incl += t;
    }
    int pos = incl - cnt;                 // exclusive prefix
    unsigned long long kw = keepw;
    while (kw) {
        int b = __ffsll((unsigned long long)kw) - 1;
        kw &= kw - 1ull;
        if (pos < K_POST) ws->rows[pos] = lane * 64 + b;
        ++pos;
    }
    int total = __shfl(incl, 63);
    if (lane == 0) ws->nk = total;
    int start = total < K_POST ? total : K_POST;
    for (int r = start + lane; r < K_POST; r += 64) ws->rows[r] = -1;
}

// ---------------------------------------------------------------------------
// Kernel 5: ROIAlign. grid = (49, 512), block = 256: one output element per
// thread (coalesced stores). Invalid rows -> exact zeros.
// ---------------------------------------------------------------------------
__global__ __launch_bounds__(256) void roi_k(const float* __restrict__ feat,
                                             const Ws* __restrict__ ws,
                                             float* __restrict__ out) {
    const int b = blockIdx.y;
    const int o = blockIdx.x * 256 + threadIdx.x;   // 0..12543
    float* orow = out + (size_t)b * (FC * 49);
    const int row = ws->rows[b];
    if (row < 0) { orow[o] = 0.0f; return; }
    const float4 bx = ws->cand[row];
    const float x1 = bx.x * SCALE, y1 = bx.y * SCALE;
    const float x2 = bx.z * SCALE, y2 = bx.w * SCALE;
    const float rw = fmaxf(x2 - x1, 1.0f);
    const float rh = fmaxf(y2 - y1, 1.0f);
    const float stepx = rw / 14.0f;
    const float stepy = rh / 14.0f;
    const int c = o / 49;
    const int p = o % 49;
    const int oy = p / 7, ox = p % 7;
    const float* fc = feat + (size_t)c * (FH * FW);
    float acc = 0.0f;
    for (int sy = 0; sy < 2; ++sy) {
        float yy = y1 + ((float)(2 * oy + sy) + 0.5f) * stepy;
        float y = fminf(fmaxf(yy, 0.0f), (float)(FH - 1));
        float fy0 = floorf(y);
        int iy0 = (int)fy0;
        int iy1 = min(iy0 + 1, FH - 1);
        float ly = y - fy0;
        for (int sx = 0; sx < 2; ++sx) {
            float xx = x1 + ((float)(2 * ox + sx) + 0.5f) * stepx;
            float x = fminf(fmaxf(xx, 0.0f), (float)(FW - 1));
            float fx0 = floorf(x);
            int ix0 = (int)fx0;
            int ix1 = min(ix0 + 1, FW - 1);
            float lx = x - fx0;
            float v00 = fc[iy0 * FW + ix0];
            float v01 = fc[iy0 * FW + ix1];
            float v10 = fc[iy1 * FW + ix0];
            float v11 = fc[iy1 * FW + ix1];
            acc += v00 * (1.0f - ly) * (1.0f - lx)
                 + v01 * (1.0f - ly) * lx
                 + v10 * ly * (1.0f - lx)
                 + v11 * ly * lx;
        }
    }
    orow[o] = acc * 0.25f;
}

extern "C" void kernel_launch(void* const* d_in, const int* in_sizes, int n_in,
                              void* d_out, int out_size, void* d_ws, size_t ws_size,
                              hipStream_t stream) {
    const float* feature    = (const float*)d_in[0];
    const float* objectness = (const float*)d_in[1];
    const float* deltas     = (const float*)d_in[2];
    const float* anchors    = (const float*)d_in[3];
    Ws* ws = (Ws*)d_ws;
    float* out = (float*)d_out;

    hipLaunchKernelGGL(radix_select_k, dim3(1), dim3(1024), 0, stream, objectness, ws);
    hipLaunchKernelGGL(gather_k, dim3((N_ANCH + 255) / 256), dim3(256), 0, stream,
                       objectness, ws);
    hipLaunchKernelGGL(sort_decode_k, dim3(1), dim3(1024), 0, stream, deltas, anchors, ws);
    hipLaunchKernelGGL(nms_mask_k, dim3(K_PRE), dim3(256), 0, stream, ws);
    hipLaunchKernelGGL(nms_scan_k, dim3(1), dim3(64), 0, stream, ws);
    hipLaunchKernelGGL(roi_k, dim3(49, 512), dim3(256), 0, stream, feature, ws, out);
}

// Round 3
// 464.010 us; speedup vs baseline: 2.8342x; 1.1333x over previous
//
#include <hip/hip_runtime.h>
#include <cstdint>
#include <cstddef>

#define N_ANCH   120000
#define K_PRE    2000
#define K_POST   512
#define CAP      4096
#define NWORD    32          // ceil(K_PRE/64)
#define HBINS    4096        // top-12-bit histogram
#define IOU_THR  0.7f
#define IMGF     800.0f
#define CLIPV    4.135166556742356f
#define FH       200
#define FW       200
#define FC       256
#define SCALE    0.25f

#define TROWS    96          // scan tile rows (96*256B = 24KB; x2 buffers = 48KB LDS)
#define NTILE    21          // ceil(2000/96); last tile = 80 rows (16 | 80)
#define CH       16          // scan chunk rows (register prefetch depth)

struct Ws {
    uint32_t T;          // threshold key (bucket lower edge)
    uint32_t cnt;        // gather counter
    int32_t  nk;         // number kept after NMS
    uint32_t pad;
    unsigned long long combo[CAP];   // (~key)<<32 | index, sorted ascending
    float4   cand[K_PRE];            // decoded candidate boxes, score-desc order
    int      rows[K_POST];           // candidate rank per output row, -1 = invalid
    unsigned long long mask[(size_t)K_PRE * NWORD];  // IoU bitmask (words >= i>>6 only)
    // NOTE: first 16KB of mask doubles as the uint32 hist[4096] (used before mask)
};

// Monotonic float -> uint key (larger float => larger uint). No NaNs expected.
__device__ inline uint32_t fkey(float f) {
    uint32_t u = __float_as_uint(f);
    return (u & 0x80000000u) ? ~u : (u | 0x80000000u);
}

// ---------------------------------------------------------------------------
// Kernel 0: zero the histogram (aliased onto mask region) + counters.
// ---------------------------------------------------------------------------
__global__ __launch_bounds__(1024) void zero_k(Ws* __restrict__ ws) {
    uint32_t* h = (uint32_t*)ws->mask;
    for (int i = threadIdx.x; i < HBINS; i += 1024) h[i] = 0u;
    if (threadIdx.x == 0) { ws->cnt = 0u; ws->nk = 0; ws->T = 0u; }
}

// ---------------------------------------------------------------------------
// Kernel 1: grid-wide 4096-bin histogram of top-12 key bits (LDS-privatized).
// ---------------------------------------------------------------------------
__global__ __launch_bounds__(256) void hist_k(const float* __restrict__ obj,
                                              uint32_t* __restrict__ hist) {
    __shared__ uint32_t h[HBINS];
    for (int i = threadIdx.x; i < HBINS; i += 256) h[i] = 0u;
    __syncthreads();
    for (int i = blockIdx.x * 256 + threadIdx.x; i < N_ANCH; i += gridDim.x * 256) {
        uint32_t u = fkey(obj[i]);
        atomicAdd(&h[u >> 20], 1u);
    }
    __syncthreads();
    for (int i = threadIdx.x; i < HBINS; i += 256)
        if (h[i]) atomicAdd(&hist[i], h[i]);
}

// ---------------------------------------------------------------------------
// Kernel 2: find threshold bucket: largest bin B with suffix-count >= K_PRE.
// T = B<<20 (bucket lower edge). Gathered count is then in [K_PRE, K_PRE+|B|].
// Block-wide prefix scan over reversed bins.
// ---------------------------------------------------------------------------
__global__ __launch_bounds__(1024) void resolve_k(const uint32_t* __restrict__ hist,
                                                  Ws* __restrict__ ws) {
    __shared__ uint32_t wsum[16];
    const int tid = threadIdx.x;
    const int lane = tid & 63, wave = tid >> 6;
    uint32_t c[4]; uint32_t s = 0;
#pragma unroll
    for (int k = 0; k < 4; ++k) { c[k] = hist[HBINS - 1 - (4 * tid + k)]; s += c[k]; }
    uint32_t incl = s;
    for (int off = 1; off < 64; off <<= 1) {
        uint32_t t = __shfl_up(incl, off);
        if (lane >= off) incl += t;
    }
    if (lane == 63) wsum[wave] = incl;
    __syncthreads();
    uint32_t wpre = 0;
    for (int w2 = 0; w2 < wave; ++w2) wpre += wsum[w2];
    uint32_t before = wpre + incl - s;
#pragma unroll
    for (int k = 0; k < 4; ++k) {
        uint32_t after = before + c[k];
        if (before < K_PRE && after >= K_PRE)
            ws->T = (uint32_t)(HBINS - 1 - (4 * tid + k)) << 20;
        before = after;
    }
}

// ---------------------------------------------------------------------------
// Kernel 3: grid-wide gather of all elements with key >= T.
// ---------------------------------------------------------------------------
__global__ void gather_k(const float* __restrict__ obj, Ws* __restrict__ ws) {
    int i = blockIdx.x * blockDim.x + threadIdx.x;
    if (i >= N_ANCH) return;
    const uint32_t T = ws->T;
    uint32_t u = fkey(obj[i]);
    if (u >= T) {
        uint32_t pos = atomicAdd(&ws->cnt, 1u);
        if (pos < CAP)
            ws->combo[pos] = ((unsigned long long)(~u) << 32) | (uint32_t)i;
    }
}

// ---------------------------------------------------------------------------
// Kernel 4: single-block bitonic sort of <=4096 combos (ascending =>
// score desc, index asc — exact lax.top_k order), then decode top-2000 boxes.
// ---------------------------------------------------------------------------
__global__ __launch_bounds__(1024) void sort_decode_k(const float* __restrict__ deltas,
                                                      const float* __restrict__ anchors,
                                                      Ws* __restrict__ ws) {
    __shared__ unsigned long long buf[CAP];
    const int tid = threadIdx.x;
    uint32_t M = ws->cnt;
    if (M > CAP) M = CAP;
    for (int i = tid; i < CAP; i += 1024)
        buf[i] = (i < (int)M) ? ws->combo[i] : 0xFFFFFFFFFFFFFFFFull;
    __syncthreads();
    for (int k = 2; k <= CAP; k <<= 1) {
        for (int j = k >> 1; j > 0; j >>= 1) {
            for (int i = tid; i < CAP; i += 1024) {
                int ixj = i ^ j;
                if (ixj > i) {
                    bool up = ((i & k) == 0);
                    unsigned long long a = buf[i], b = buf[ixj];
                    if ((a > b) == up) { buf[i] = b; buf[ixj] = a; }
                }
            }
            __syncthreads();
        }
    }
    for (int r = tid; r < K_PRE; r += 1024) {
        uint32_t idx = (uint32_t)(buf[r] & 0xFFFFFFFFull);
        float a0 = anchors[idx * 4 + 0], a1 = anchors[idx * 4 + 1];
        float a2 = anchors[idx * 4 + 2], a3 = anchors[idx * 4 + 3];
        float d0 = deltas[idx * 4 + 0],  d1 = deltas[idx * 4 + 1];
        float d2 = fminf(deltas[idx * 4 + 2], CLIPV);
        float d3 = fminf(deltas[idx * 4 + 3], CLIPV);
        float w = a2 - a0, h = a3 - a1;
        float cx = a0 + 0.5f * w, cy = a1 + 0.5f * h;
        float pcx = d0 * w + cx, pcy = d1 * h + cy;
        float pw = expf(d2) * w, ph = expf(d3) * h;
        float x1 = fminf(fmaxf(pcx - 0.5f * pw, 0.0f), IMGF);
        float y1 = fminf(fmaxf(pcy - 0.5f * ph, 0.0f), IMGF);
        float x2 = fminf(fmaxf(pcx + 0.5f * pw, 0.0f), IMGF);
        float y2 = fminf(fmaxf(pcy + 0.5f * ph, 0.0f), IMGF);
        ws->cand[r] = make_float4(x1, y1, x2, y2);
    }
}

// ---------------------------------------------------------------------------
// Kernel 5a: build the pairwise suppression bitmask.
// mask[i][w] bit b set  <=>  j = 64w+b, j > i, j < K_PRE, IoU(i,j) > thr.
// Only words w >= i>>6 are written (lower words are all-zero by j>i and are
// masked out at load time in the scan).
// ---------------------------------------------------------------------------
__global__ __launch_bounds__(256) void nms_mask_k(Ws* __restrict__ ws) {
    const int i = blockIdx.x;
    const int lane = threadIdx.x & 63;
    const int wave = threadIdx.x >> 6;
    const int w0 = i >> 6;
    const float4 bi = ws->cand[i];
    const float ai = (bi.z - bi.x) * (bi.w - bi.y);
    for (int wd = w0 + wave; wd < NWORD; wd += 4) {
        int j = wd * 64 + lane;
        bool bit = false;
        if (j < K_PRE && j > i) {
            float4 bj = ws->cand[j];
            float aj = (bj.z - bj.x) * (bj.w - bj.y);
            float xx1 = fmaxf(bi.x, bj.x);
            float yy1 = fmaxf(bi.y, bj.y);
            float xx2 = fminf(bi.z, bj.z);
            float yy2 = fminf(bi.w, bj.w);
            float ww = fmaxf(xx2 - xx1, 0.0f);
            float hh = fmaxf(yy2 - yy1, 0.0f);
            float inter = ww * hh;
            float iou = inter / (ai + aj - inter + 1e-6f);
            bit = iou > IOU_THR;
        }
        unsigned long long bal = __ballot(bit);
        if (lane == 0) ws->mask[(size_t)i * NWORD + wd] = bal;
    }
}

// ---------------------------------------------------------------------------
// Kernel 5b: greedy scan. 1024 threads: wave 0 scans tile t from LDS while
// waves 1-15 stage tile t+1 (double-buffered). Wave 0 uses an explicit
// register double-buffer (A/B, CH=16 rows) so LDS latency is off the serial
// chain; serial work per row is ~4 VALU ops. Lane L owns supp word L.
// ---------------------------------------------------------------------------
__global__ __launch_bounds__(1024) void nms_scan_k(Ws* __restrict__ ws) {
    __shared__ unsigned long long sbuf[2][TROWS * NWORD];
    const int tid = threadIdx.x;
    const int lane = tid & 63;
    const int wave = tid >> 6;
    const unsigned long long* __restrict__ mask = ws->mask;

    // stage tile 0 (all threads)
    for (int e = tid; e < TROWS * NWORD; e += 1024) sbuf[0][e] = mask[e];
    __syncthreads();

    unsigned long long supp = 0ull;
    for (int t = 0; t < NTILE; ++t) {
        const int base = t * TROWS;
        const int nb = min(TROWS, K_PRE - base);
        if (wave == 0) {
            const unsigned long long* sm = sbuf[t & 1];
            unsigned long long A[CH], B[CH];
            auto loadc = [&](unsigned long long* rm, int s) {
                const int w = (base + s) >> 6;
                const bool rl = (lane >= w) && (lane < NWORD);
#pragma unroll
                for (int b = 0; b < CH; ++b)
                    rm[b] = rl ? sm[(s + b) * NWORD + lane] : 0ull;
            };
            auto proc = [&](unsigned long long* rm, int s) {
                const int w = (base + s) >> 6;
                const int bofs = (base + s) & 63;
                unsigned long long colw[CH];
#pragma unroll
                for (int b = 0; b < CH; ++b) colw[b] = __shfl(rm[b], w);
                unsigned long long cur = __shfl(supp, w);
#pragma unroll
                for (int b = 0; b < CH; ++b) {
                    if (!((cur >> (bofs + b)) & 1ull)) { cur |= colw[b]; supp |= rm[b]; }
                }
            };
            loadc(A, 0);
            for (int s = 0; s < nb; s += 2 * CH) {
                const bool hasB = (s + CH) < nb;
                if (hasB) loadc(B, s + CH);
                proc(A, s);
                if (hasB) {
                    if (s + 2 * CH < nb) loadc(A, s + 2 * CH);
                    proc(B, s + CH);
                }
            }
        } else if (t + 1 < NTILE) {
            const int nbase = (t + 1) * TROWS;
            const int cnt2 = min(TROWS, K_PRE - nbase) * NWORD;
            const unsigned long long* src = mask + (size_t)nbase * NWORD;
            unsigned long long* dst = sbuf[(t + 1) & 1];
            for (int e = tid - 64; e < cnt2; e += 960) dst[e] = src[e];
        }
        __syncthreads();
    }

    if (wave == 0) {
        // ---- compaction: kept = ~supp (valid bits only) ----
        unsigned long long valid;
        if (lane < NWORD - 1)       valid = ~0ull;
        else if (lane == NWORD - 1) valid = (1ull << (K_PRE - (NWORD - 1) * 64)) - 1ull;
        else                        valid = 0ull;
        unsigned long long keepw = (~supp) & valid;
        int cnt = __popcll(keepw);
        int incl = cnt;
        for (int off = 1; off < 64; off <<= 1) {
            int t = __shfl_up(incl, off);
            if (lane >= off) incl += t;
        }
        int pos = incl - cnt;
        unsigned long long kw = keepw;
        while (kw) {
            int b = __ffsll((unsigned long long)kw) - 1;
            kw &= kw - 1ull;
            if (pos < K_POST) ws->rows[pos] = lane * 64 + b;
            ++pos;
        }
        int total = __shfl(incl, 63);
        if (lane == 0) ws->nk = total;
        int start = total < K_POST ? total : K_POST;
        for (int r = start + lane; r < K_POST; r += 64) ws->rows[r] = -1;
    }
}

// ---------------------------------------------------------------------------
// Kernel 6: ROIAlign. grid = (49, 512), block = 256: one output element per
// thread (coalesced stores). Invalid rows -> exact zeros.
// ---------------------------------------------------------------------------
__global__ __launch_bounds__(256) void roi_k(const float* __restrict__ feat,
                                             const Ws* __restrict__ ws,
                                             float* __restrict__ out) {
    const int b = blockIdx.y;
    const int o = blockIdx.x * 256 + threadIdx.x;   // 0..12543
    float* orow = out + (size_t)b * (FC * 49);
    const int row = ws->rows[b];
    if (row < 0) { orow[o] = 0.0f; return; }
    const float4 bx = ws->cand[row];
    const float x1 = bx.x * SCALE, y1 = bx.y * SCALE;
    const float x2 = bx.z * SCALE, y2 = bx.w * SCALE;
    const float rw = fmaxf(x2 - x1, 1.0f);
    const float rh = fmaxf(y2 - y1, 1.0f);
    const float stepx = rw / 14.0f;
    const float stepy = rh / 14.0f;
    const int c = o / 49;
    const int p = o % 49;
    const int oy = p / 7, ox = p % 7;
    const float* fc = feat + (size_t)c * (FH * FW);
    float acc = 0.0f;
    for (int sy = 0; sy < 2; ++sy) {
        float yy = y1 + ((float)(2 * oy + sy) + 0.5f) * stepy;
        float y = fminf(fmaxf(yy, 0.0f), (float)(FH - 1));
        float fy0 = floorf(y);
        int iy0 = (int)fy0;
        int iy1 = min(iy0 + 1, FH - 1);
        float ly = y - fy0;
        for (int sx = 0; sx < 2; ++sx) {
            float xx = x1 + ((float)(2 * ox + sx) + 0.5f) * stepx;
            float x = fminf(fmaxf(xx, 0.0f), (float)(FW - 1));
            float fx0 = floorf(x);
            int ix0 = (int)fx0;
            int ix1 = min(ix0 + 1, FW - 1);
            float lx = x - fx0;
            float v00 = fc[iy0 * FW + ix0];
            float v01 = fc[iy0 * FW + ix1];
            float v10 = fc[iy1 * FW + ix0];
            float v11 = fc[iy1 * FW + ix1];
            acc += v00 * (1.0f - ly) * (1.0f - lx)
                 + v01 * (1.0f - ly) * lx
                 + v10 * ly * (1.0f - lx)
                 + v11 * ly * lx;
        }
    }
    orow[o] = acc * 0.25f;
}

extern "C" void kernel_launch(void* const* d_in, const int* in_sizes, int n_in,
                              void* d_out, int out_size, void* d_ws, size_t ws_size,
                              hipStream_t stream) {
    const float* feature    = (const float*)d_in[0];
    const float* objectness = (const float*)d_in[1];
    const float* deltas     = (const float*)d_in[2];
    const float* anchors    = (const float*)d_in[3];
    Ws* ws = (Ws*)d_ws;
    uint32_t* hist = (uint32_t*)ws->mask;   // alias: hist lives in (pre-)mask space
    float* out = (float*)d_out;

    hipLaunchKernelGGL(zero_k, dim3(1), dim3(1024), 0, stream, ws);
    hipLaunchKernelGGL(hist_k, dim3(256), dim3(256), 0, stream, objectness, hist);
    hipLaunchKernelGGL(resolve_k, dim3(1), dim3(1024), 0, stream, hist, ws);
    hipLaunchKernelGGL(gather_k, dim3((N_ANCH + 255) / 256), dim3(256), 0, stream,
                       objectness, ws);
    hipLaunchKernelGGL(sort_decode_k, dim3(1), dim3(1024), 0, stream, deltas, anchors, ws);
    hipLaunchKernelGGL(nms_mask_k, dim3(K_PRE), dim3(256), 0, stream, ws);
    hipLaunchKernelGGL(nms_scan_k, dim3(1), dim3(1024), 0, stream, ws);
    hipLaunchKernelGGL(roi_k, dim3(49, 512), dim3(256), 0, stream, feature, ws, out);
}

// Round 4
// 419.782 us; speedup vs baseline: 3.1328x; 1.1054x over previous
//
#include <hip/hip_runtime.h>
#include <cstdint>
#include <cstddef>

#define N_ANCH   120000
#define K_PRE    2000
#define K_POST   512
#define CAP      4096
#define NWORD    32          // ceil(K_PRE/64)
#define HBINS    4096        // top-12-bit histogram
#define IOU_THR  0.7f
#define IMGF     800.0f
#define CLIPV    4.135166556742356f
#define FH       200
#define FW       200
#define FC       256
#define SCALE    0.25f

#define TROWS    96          // scan tile rows (96*256B = 24KB; x2 buffers = 48KB LDS)
#define NTILE    21          // ceil(2000/96); last tile = 80 rows
#define CH       8           // scan chunk rows (register prefetch depth)

struct Ws {
    uint32_t T;          // threshold key (bucket lower edge)
    uint32_t cnt;        // gather counter
    int32_t  nk;         // number kept after NMS
    uint32_t pad;
    unsigned long long combo[CAP];   // (~key)<<32 | index, sorted ascending
    float4   cand[K_PRE];            // decoded candidate boxes, score-desc order
    int      rows[K_POST];           // candidate rank per output row, -1 = invalid
    unsigned long long mask[(size_t)K_PRE * NWORD];  // IoU bitmask (words >= i>>6 only)
    // NOTE: first 16KB of mask doubles as the uint32 hist[4096] (used before mask)
};

// Monotonic float -> uint key (larger float => larger uint). No NaNs expected.
__device__ inline uint32_t fkey(float f) {
    uint32_t u = __float_as_uint(f);
    return (u & 0x80000000u) ? ~u : (u | 0x80000000u);
}

// ---------------------------------------------------------------------------
// Kernel 0: zero the histogram (aliased onto mask region) + counters.
// ---------------------------------------------------------------------------
__global__ __launch_bounds__(1024) void zero_k(Ws* __restrict__ ws) {
    uint32_t* h = (uint32_t*)ws->mask;
    for (int i = threadIdx.x; i < HBINS; i += 1024) h[i] = 0u;
    if (threadIdx.x == 0) { ws->cnt = 0u; ws->nk = 0; ws->T = 0u; }
}

// ---------------------------------------------------------------------------
// Kernel 1: grid-wide 4096-bin histogram of top-12 key bits (LDS-privatized).
// ---------------------------------------------------------------------------
__global__ __launch_bounds__(256) void hist_k(const float* __restrict__ obj,
                                              uint32_t* __restrict__ hist) {
    __shared__ uint32_t h[HBINS];
    for (int i = threadIdx.x; i < HBINS; i += 256) h[i] = 0u;
    __syncthreads();
    for (int i = blockIdx.x * 256 + threadIdx.x; i < N_ANCH; i += gridDim.x * 256) {
        uint32_t u = fkey(obj[i]);
        atomicAdd(&h[u >> 20], 1u);
    }
    __syncthreads();
    for (int i = threadIdx.x; i < HBINS; i += 256)
        if (h[i]) atomicAdd(&hist[i], h[i]);
}

// ---------------------------------------------------------------------------
// Kernel 2: find threshold bucket: largest bin B with suffix-count >= K_PRE.
// T = B<<20 (bucket lower edge). Gathered count is then in [K_PRE, K_PRE+|B|].
// ---------------------------------------------------------------------------
__global__ __launch_bounds__(1024) void resolve_k(const uint32_t* __restrict__ hist,
                                                  Ws* __restrict__ ws) {
    __shared__ uint32_t wsum[16];
    const int tid = threadIdx.x;
    const int lane = tid & 63, wave = tid >> 6;
    uint32_t c[4]; uint32_t s = 0;
#pragma unroll
    for (int k = 0; k < 4; ++k) { c[k] = hist[HBINS - 1 - (4 * tid + k)]; s += c[k]; }
    uint32_t incl = s;
    for (int off = 1; off < 64; off <<= 1) {
        uint32_t t = __shfl_up(incl, off);
        if (lane >= off) incl += t;
    }
    if (lane == 63) wsum[wave] = incl;
    __syncthreads();
    uint32_t wpre = 0;
    for (int w2 = 0; w2 < wave; ++w2) wpre += wsum[w2];
    uint32_t before = wpre + incl - s;
#pragma unroll
    for (int k = 0; k < 4; ++k) {
        uint32_t after = before + c[k];
        if (before < K_PRE && after >= K_PRE)
            ws->T = (uint32_t)(HBINS - 1 - (4 * tid + k)) << 20;
        before = after;
    }
}

// ---------------------------------------------------------------------------
// Kernel 3: grid-wide gather of all elements with key >= T.
// ---------------------------------------------------------------------------
__global__ void gather_k(const float* __restrict__ obj, Ws* __restrict__ ws) {
    int i = blockIdx.x * blockDim.x + threadIdx.x;
    if (i >= N_ANCH) return;
    const uint32_t T = ws->T;
    uint32_t u = fkey(obj[i]);
    if (u >= T) {
        uint32_t pos = atomicAdd(&ws->cnt, 1u);
        if (pos < CAP)
            ws->combo[pos] = ((unsigned long long)(~u) << 32) | (uint32_t)i;
    }
}

// ---------------------------------------------------------------------------
// Kernel 4: single-block bitonic sort of <=4096 combos (ascending =>
// score desc, index asc — exact lax.top_k order), then decode top-2000 boxes.
// ---------------------------------------------------------------------------
__global__ __launch_bounds__(1024) void sort_decode_k(const float* __restrict__ deltas,
                                                      const float* __restrict__ anchors,
                                                      Ws* __restrict__ ws) {
    __shared__ unsigned long long buf[CAP];
    const int tid = threadIdx.x;
    uint32_t M = ws->cnt;
    if (M > CAP) M = CAP;
    for (int i = tid; i < CAP; i += 1024)
        buf[i] = (i < (int)M) ? ws->combo[i] : 0xFFFFFFFFFFFFFFFFull;
    __syncthreads();
    for (int k = 2; k <= CAP; k <<= 1) {
        for (int j = k >> 1; j > 0; j >>= 1) {
            for (int i = tid; i < CAP; i += 1024) {
                int ixj = i ^ j;
                if (ixj > i) {
                    bool up = ((i & k) == 0);
                    unsigned long long a = buf[i], b = buf[ixj];
                    if ((a > b) == up) { buf[i] = b; buf[ixj] = a; }
                }
            }
            __syncthreads();
        }
    }
    for (int r = tid; r < K_PRE; r += 1024) {
        uint32_t idx = (uint32_t)(buf[r] & 0xFFFFFFFFull);
        float a0 = anchors[idx * 4 + 0], a1 = anchors[idx * 4 + 1];
        float a2 = anchors[idx * 4 + 2], a3 = anchors[idx * 4 + 3];
        float d0 = deltas[idx * 4 + 0],  d1 = deltas[idx * 4 + 1];
        float d2 = fminf(deltas[idx * 4 + 2], CLIPV);
        float d3 = fminf(deltas[idx * 4 + 3], CLIPV);
        float w = a2 - a0, h = a3 - a1;
        float cx = a0 + 0.5f * w, cy = a1 + 0.5f * h;
        float pcx = d0 * w + cx, pcy = d1 * h + cy;
        float pw = expf(d2) * w, ph = expf(d3) * h;
        float x1 = fminf(fmaxf(pcx - 0.5f * pw, 0.0f), IMGF);
        float y1 = fminf(fmaxf(pcy - 0.5f * ph, 0.0f), IMGF);
        float x2 = fminf(fmaxf(pcx + 0.5f * pw, 0.0f), IMGF);
        float y2 = fminf(fmaxf(pcy + 0.5f * ph, 0.0f), IMGF);
        ws->cand[r] = make_float4(x1, y1, x2, y2);
    }
}

// ---------------------------------------------------------------------------
// Kernel 5a: build the pairwise suppression bitmask.
// mask[i][w] bit b set  <=>  j = 64w+b, j > i, j < K_PRE, IoU(i,j) > thr.
// Only words w >= i>>6 are written.
// ---------------------------------------------------------------------------
__global__ __launch_bounds__(256) void nms_mask_k(Ws* __restrict__ ws) {
    const int i = blockIdx.x;
    const int lane = threadIdx.x & 63;
    const int wave = threadIdx.x >> 6;
    const int w0 = i >> 6;
    const float4 bi = ws->cand[i];
    const float ai = (bi.z - bi.x) * (bi.w - bi.y);
    for (int wd = w0 + wave; wd < NWORD; wd += 4) {
        int j = wd * 64 + lane;
        bool bit = false;
        if (j < K_PRE && j > i) {
            float4 bj = ws->cand[j];
            float aj = (bj.z - bj.x) * (bj.w - bj.y);
            float xx1 = fmaxf(bi.x, bj.x);
            float yy1 = fmaxf(bi.y, bj.y);
            float xx2 = fminf(bi.z, bj.z);
            float yy2 = fminf(bi.w, bj.w);
            float ww = fmaxf(xx2 - xx1, 0.0f);
            float hh = fmaxf(yy2 - yy1, 0.0f);
            float inter = ww * hh;
            float iou = inter / (ai + aj - inter + 1e-6f);
            bit = iou > IOU_THR;
        }
        unsigned long long bal = __ballot(bit);
        if (lane == 0) ws->mask[(size_t)i * NWORD + wd] = bal;
    }
}

// ---------------------------------------------------------------------------
// Kernel 5b: greedy scan. 256 threads (launch_bounds(256) => allocator may use
// up to 256 VGPRs — round-3 lesson: 1024-thread bounds forced a 64-VGPR cap
// and spilled the prefetch arrays to scratch, 56KB of spill traffic/dispatch).
// Wave 0 scans tile t from LDS via a CH=8 register double-buffer (A/B);
// waves 1-3 stage tile t+1 with ulonglong2 (16B) loads. Lane L owns supp
// word L. Chunks never straddle a 64-row word boundary (96 mod 64 = 32,
// 8 | all offsets), so one __shfl broadcast per chunk suffices.
// ---------------------------------------------------------------------------
__global__ __launch_bounds__(256) void nms_scan_k(Ws* __restrict__ ws) {
    __shared__ __align__(16) unsigned long long sbuf[2][TROWS * NWORD];
    const int tid = threadIdx.x;
    const int lane = tid & 63;
    const int wave = tid >> 6;
    const unsigned long long* __restrict__ mask = ws->mask;

    // stage tile 0 (all threads, 16B vector loads)
    {
        const ulonglong2* src = (const ulonglong2*)mask;
        ulonglong2* dst = (ulonglong2*)sbuf[0];
        for (int e = tid; e < TROWS * NWORD / 2; e += 256) dst[e] = src[e];
    }
    __syncthreads();

    unsigned long long supp = 0ull;
    for (int t = 0; t < NTILE; ++t) {
        const int base = t * TROWS;
        const int nb = min(TROWS, K_PRE - base);
        if (wave == 0) {
            const unsigned long long* sm = sbuf[t & 1];
            unsigned long long A[CH], B[CH];
            auto loadc = [&](unsigned long long* rm, int s) {
                const int w = (base + s) >> 6;
                const bool rl = (lane >= w) && (lane < NWORD);
#pragma unroll
                for (int b = 0; b < CH; ++b)
                    rm[b] = rl ? sm[(s + b) * NWORD + lane] : 0ull;
            };
            auto proc = [&](unsigned long long* rm, int s) {
                const int w = (base + s) >> 6;
                const int bofs = (base + s) & 63;
                unsigned long long colw[CH];
#pragma unroll
                for (int b = 0; b < CH; ++b) colw[b] = __shfl(rm[b], w);
                unsigned long long cur = __shfl(supp, w);
#pragma unroll
                for (int b = 0; b < CH; ++b) {
                    if (!((cur >> (bofs + b)) & 1ull)) { cur |= colw[b]; supp |= rm[b]; }
                }
            };
            loadc(A, 0);
            for (int s = 0; s < nb; s += 2 * CH) {
                const bool hasB = (s + CH) < nb;
                if (hasB) loadc(B, s + CH);
                proc(A, s);
                if (hasB) {
                    if (s + 2 * CH < nb) loadc(A, s + 2 * CH);
                    proc(B, s + CH);
                }
            }
        } else if (t + 1 < NTILE) {
            const int nbase = (t + 1) * TROWS;
            const int npairs = (min(TROWS, K_PRE - nbase) * NWORD) / 2;
            const ulonglong2* src = (const ulonglong2*)(mask + (size_t)nbase * NWORD);
            ulonglong2* dst = (ulonglong2*)sbuf[(t + 1) & 1];
            for (int e = tid - 64; e < npairs; e += 192) dst[e] = src[e];
        }
        __syncthreads();
    }

    if (wave == 0) {
        // ---- compaction: kept = ~supp (valid bits only) ----
        unsigned long long valid;
        if (lane < NWORD - 1)       valid = ~0ull;
        else if (lane == NWORD - 1) valid = (1ull << (K_PRE - (NWORD - 1) * 64)) - 1ull;
        else                        valid = 0ull;
        unsigned long long keepw = (~supp) & valid;
        int cnt = __popcll(keepw);
        int incl = cnt;
        for (int off = 1; off < 64; off <<= 1) {
            int t = __shfl_up(incl, off);
            if (lane >= off) incl += t;
        }
        int pos = incl - cnt;
        unsigned long long kw = keepw;
        while (kw) {
            int b = __ffsll((unsigned long long)kw) - 1;
            kw &= kw - 1ull;
            if (pos < K_POST) ws->rows[pos] = lane * 64 + b;
            ++pos;
        }
        int total = __shfl(incl, 63);
        if (lane == 0) ws->nk = total;
        int start = total < K_POST ? total : K_POST;
        for (int r = start + lane; r < K_POST; r += 64) ws->rows[r] = -1;
    }
}

// ---------------------------------------------------------------------------
// Kernel 6: ROIAlign. grid = (49, 512), block = 256: one output element per
// thread (coalesced stores). Invalid rows -> exact zeros.
// ---------------------------------------------------------------------------
__global__ __launch_bounds__(256) void roi_k(const float* __restrict__ feat,
                                             const Ws* __restrict__ ws,
                                             float* __restrict__ out) {
    const int b = blockIdx.y;
    const int o = blockIdx.x * 256 + threadIdx.x;   // 0..12543
    float* orow = out + (size_t)b * (FC * 49);
    const int row = ws->rows[b];
    if (row < 0) { orow[o] = 0.0f; return; }
    const float4 bx = ws->cand[row];
    const float x1 = bx.x * SCALE, y1 = bx.y * SCALE;
    const float x2 = bx.z * SCALE, y2 = bx.w * SCALE;
    const float rw = fmaxf(x2 - x1, 1.0f);
    const float rh = fmaxf(y2 - y1, 1.0f);
    const float stepx = rw / 14.0f;
    const float stepy = rh / 14.0f;
    const int c = o / 49;
    const int p = o % 49;
    const int oy = p / 7, ox = p % 7;
    const float* fc = feat + (size_t)c * (FH * FW);
    float acc = 0.0f;
    for (int sy = 0; sy < 2; ++sy) {
        float yy = y1 + ((float)(2 * oy + sy) + 0.5f) * stepy;
        float y = fminf(fmaxf(yy, 0.0f), (float)(FH - 1));
        float fy0 = floorf(y);
        int iy0 = (int)fy0;
        int iy1 = min(iy0 + 1, FH - 1);
        float ly = y - fy0;
        for (int sx = 0; sx < 2; ++sx) {
            float xx = x1 + ((float)(2 * ox + sx) + 0.5f) * stepx;
            float x = fminf(fmaxf(xx, 0.0f), (float)(FW - 1));
            float fx0 = floorf(x);
            int ix0 = (int)fx0;
            int ix1 = min(ix0 + 1, FW - 1);
            float lx = x - fx0;
            float v00 = fc[iy0 * FW + ix0];
            float v01 = fc[iy0 * FW + ix1];
            float v10 = fc[iy1 * FW + ix0];
            float v11 = fc[iy1 * FW + ix1];
            acc += v00 * (1.0f - ly) * (1.0f - lx)
                 + v01 * (1.0f - ly) * lx
                 + v10 * ly * (1.0f - lx)
                 + v11 * ly * lx;
        }
    }
    orow[o] = acc * 0.25f;
}

extern "C" void kernel_launch(void* const* d_in, const int* in_sizes, int n_in,
                              void* d_out, int out_size, void* d_ws, size_t ws_size,
                              hipStream_t stream) {
    const float* feature    = (const float*)d_in[0];
    const float* objectness = (const float*)d_in[1];
    const float* deltas     = (const float*)d_in[2];
    const float* anchors    = (const float*)d_in[3];
    Ws* ws = (Ws*)d_ws;
    uint32_t* hist = (uint32_t*)ws->mask;   // alias: hist lives in (pre-)mask space
    float* out = (float*)d_out;

    hipLaunchKernelGGL(zero_k, dim3(1), dim3(1024), 0, stream, ws);
    hipLaunchKernelGGL(hist_k, dim3(256), dim3(256), 0, stream, objectness, hist);
    hipLaunchKernelGGL(resolve_k, dim3(1), dim3(1024), 0, stream, hist, ws);
    hipLaunchKernelGGL(gather_k, dim3((N_ANCH + 255) / 256), dim3(256), 0, stream,
                       objectness, ws);
    hipLaunchKernelGGL(sort_decode_k, dim3(1), dim3(1024), 0, stream, deltas, anchors, ws);
    hipLaunchKernelGGL(nms_mask_k, dim3(K_PRE), dim3(256), 0, stream, ws);
    hipLaunchKernelGGL(nms_scan_k, dim3(1), dim3(256), 0, stream, ws);
    hipLaunchKernelGGL(roi_k, dim3(49, 512), dim3(256), 0, stream, feature, ws, out);
}

// Round 5
// 332.663 us; speedup vs baseline: 3.9533x; 1.2619x over previous
//
#include <hip/hip_runtime.h>
#include <cstdint>
#include <cstddef>

#define N_ANCH   120000
#define K_PRE    2000
#define K_POST   512
#define CAP      4096
#define NWORD    32          // ceil(K_PRE/64)
#define HBINS    4096        // top-12-bit histogram
#define IOU_THR  0.7f
#define IMGF     800.0f
#define CLIPV    4.135166556742356f
#define FH       200
#define FW       200
#define FC       256
#define SCALE    0.25f

#define TROWS    96          // scan tile rows (96*256B = 24KB; x2 buffers = 48KB LDS)
#define NTILE    21          // ceil(2000/96); last tile = 80 rows
#define CH       8           // scan chunk rows (register prefetch depth)

typedef unsigned long long u64;

struct Ws {
    uint32_t T;          // threshold key (bucket lower edge)
    uint32_t cnt;        // gather counter
    int32_t  nk;         // number kept after NMS
    uint32_t pad;
    u64      combo[CAP];             // (~key)<<32 | index, sorted ascending
    float4   cand[K_PRE];            // decoded candidate boxes, score-desc order
    int      rows[K_POST];           // candidate rank per output row, -1 = invalid
    u64      mask[(size_t)K_PRE * NWORD];  // IoU bitmask, ALL 32 words written
    // NOTE: first 16KB of mask doubles as the uint32 hist[4096] (used before mask)
};

// Monotonic float -> uint key (larger float => larger uint). No NaNs expected.
__device__ inline uint32_t fkey(float f) {
    uint32_t u = __float_as_uint(f);
    return (u & 0x80000000u) ? ~u : (u | 0x80000000u);
}

// ---------------------------------------------------------------------------
// Kernel 0: zero the histogram (aliased onto mask region) + counters.
// ---------------------------------------------------------------------------
__global__ __launch_bounds__(1024) void zero_k(Ws* __restrict__ ws) {
    uint32_t* h = (uint32_t*)ws->mask;
    for (int i = threadIdx.x; i < HBINS; i += 1024) h[i] = 0u;
    if (threadIdx.x == 0) { ws->cnt = 0u; ws->nk = 0; ws->T = 0u; }
}

// ---------------------------------------------------------------------------
// Kernel 1: grid-wide 4096-bin histogram of top-12 key bits (LDS-privatized).
// ---------------------------------------------------------------------------
__global__ __launch_bounds__(256) void hist_k(const float* __restrict__ obj,
                                              uint32_t* __restrict__ hist) {
    __shared__ uint32_t h[HBINS];
    for (int i = threadIdx.x; i < HBINS; i += 256) h[i] = 0u;
    __syncthreads();
    for (int i = blockIdx.x * 256 + threadIdx.x; i < N_ANCH; i += gridDim.x * 256) {
        uint32_t u = fkey(obj[i]);
        atomicAdd(&h[u >> 20], 1u);
    }
    __syncthreads();
    for (int i = threadIdx.x; i < HBINS; i += 256)
        if (h[i]) atomicAdd(&hist[i], h[i]);
}

// ---------------------------------------------------------------------------
// Kernel 2: find threshold bucket: largest bin B with suffix-count >= K_PRE.
// ---------------------------------------------------------------------------
__global__ __launch_bounds__(1024) void resolve_k(const uint32_t* __restrict__ hist,
                                                  Ws* __restrict__ ws) {
    __shared__ uint32_t wsum[16];
    const int tid = threadIdx.x;
    const int lane = tid & 63, wave = tid >> 6;
    uint32_t c[4]; uint32_t s = 0;
#pragma unroll
    for (int k = 0; k < 4; ++k) { c[k] = hist[HBINS - 1 - (4 * tid + k)]; s += c[k]; }
    uint32_t incl = s;
    for (int off = 1; off < 64; off <<= 1) {
        uint32_t t = __shfl_up(incl, off);
        if (lane >= off) incl += t;
    }
    if (lane == 63) wsum[wave] = incl;
    __syncthreads();
    uint32_t wpre = 0;
    for (int w2 = 0; w2 < wave; ++w2) wpre += wsum[w2];
    uint32_t before = wpre + incl - s;
#pragma unroll
    for (int k = 0; k < 4; ++k) {
        uint32_t after = before + c[k];
        if (before < K_PRE && after >= K_PRE)
            ws->T = (uint32_t)(HBINS - 1 - (4 * tid + k)) << 20;
        before = after;
    }
}

// ---------------------------------------------------------------------------
// Kernel 3: grid-wide gather of all elements with key >= T.
// ---------------------------------------------------------------------------
__global__ void gather_k(const float* __restrict__ obj, Ws* __restrict__ ws) {
    int i = blockIdx.x * blockDim.x + threadIdx.x;
    if (i >= N_ANCH) return;
    const uint32_t T = ws->T;
    uint32_t u = fkey(obj[i]);
    if (u >= T) {
        uint32_t pos = atomicAdd(&ws->cnt, 1u);
        if (pos < CAP)
            ws->combo[pos] = ((u64)(~u) << 32) | (uint32_t)i;
    }
}

// ---------------------------------------------------------------------------
// Kernel 4: single-block bitonic sort of <=4096 combos (ascending =>
// score desc, index asc — exact lax.top_k order), then decode top-2000 boxes.
// ---------------------------------------------------------------------------
__global__ __launch_bounds__(1024) void sort_decode_k(const float* __restrict__ deltas,
                                                      const float* __restrict__ anchors,
                                                      Ws* __restrict__ ws) {
    __shared__ u64 buf[CAP];
    const int tid = threadIdx.x;
    uint32_t M = ws->cnt;
    if (M > CAP) M = CAP;
    for (int i = tid; i < CAP; i += 1024)
        buf[i] = (i < (int)M) ? ws->combo[i] : 0xFFFFFFFFFFFFFFFFull;
    __syncthreads();
    for (int k = 2; k <= CAP; k <<= 1) {
        for (int j = k >> 1; j > 0; j >>= 1) {
            for (int i = tid; i < CAP; i += 1024) {
                int ixj = i ^ j;
                if (ixj > i) {
                    bool up = ((i & k) == 0);
                    u64 a = buf[i], b = buf[ixj];
                    if ((a > b) == up) { buf[i] = b; buf[ixj] = a; }
                }
            }
            __syncthreads();
        }
    }
    for (int r = tid; r < K_PRE; r += 1024) {
        uint32_t idx = (uint32_t)(buf[r] & 0xFFFFFFFFull);
        float a0 = anchors[idx * 4 + 0], a1 = anchors[idx * 4 + 1];
        float a2 = anchors[idx * 4 + 2], a3 = anchors[idx * 4 + 3];
        float d0 = deltas[idx * 4 + 0],  d1 = deltas[idx * 4 + 1];
        float d2 = fminf(deltas[idx * 4 + 2], CLIPV);
        float d3 = fminf(deltas[idx * 4 + 3], CLIPV);
        float w = a2 - a0, h = a3 - a1;
        float cx = a0 + 0.5f * w, cy = a1 + 0.5f * h;
        float pcx = d0 * w + cx, pcy = d1 * h + cy;
        float pw = expf(d2) * w, ph = expf(d3) * h;
        float x1 = fminf(fmaxf(pcx - 0.5f * pw, 0.0f), IMGF);
        float y1 = fminf(fmaxf(pcy - 0.5f * ph, 0.0f), IMGF);
        float x2 = fminf(fmaxf(pcx + 0.5f * pw, 0.0f), IMGF);
        float y2 = fminf(fmaxf(pcy + 0.5f * ph, 0.0f), IMGF);
        ws->cand[r] = make_float4(x1, y1, x2, y2);
    }
}

// ---------------------------------------------------------------------------
// Kernel 5a: build the pairwise suppression bitmask.
// mask[i][w] bit b set  <=>  j = 64w+b, j > i, j < K_PRE, IoU(i,j) > thr.
// ALL 32 words are written (lower words = 0) so the scan needs no masking.
// ---------------------------------------------------------------------------
__global__ __launch_bounds__(256) void nms_mask_k(Ws* __restrict__ ws) {
    const int i = blockIdx.x;
    const int lane = threadIdx.x & 63;
    const int wave = threadIdx.x >> 6;
    const float4 bi = ws->cand[i];
    const float ai = (bi.z - bi.x) * (bi.w - bi.y);
    for (int wd = wave; wd < NWORD; wd += 4) {
        int j = wd * 64 + lane;
        bool bit = false;
        if (j < K_PRE && j > i) {
            float4 bj = ws->cand[j];
            float aj = (bj.z - bj.x) * (bj.w - bj.y);
            float xx1 = fmaxf(bi.x, bj.x);
            float yy1 = fmaxf(bi.y, bj.y);
            float xx2 = fminf(bi.z, bj.z);
            float yy2 = fminf(bi.w, bj.w);
            float ww = fmaxf(xx2 - xx1, 0.0f);
            float hh = fmaxf(yy2 - yy1, 0.0f);
            float inter = ww * hh;
            float iou = inter / (ai + aj - inter + 1e-6f);
            bit = iou > IOU_THR;
        }
        u64 bal = __ballot(bit);
        if (lane == 0) ws->mask[(size_t)i * NWORD + wd] = bal;
    }
}

// ---------------------------------------------------------------------------
// Kernel 5b: greedy scan, owner-lane formulation (round-4 lesson: per-row
// divergent branches + per-row __shfl cost ~215 cyc/row; both eliminated).
// Lane L owns supp word (L&31). Per chunk of CH=8 rows:
//   - lanes load their column of the 8 rows from LDS (A/B reg double-buffer)
//   - ONLY the owning lane w runs the serial bit loop — branchless, on its
//     private registers (its column IS the diagonal word stream)
//   - one __shfl broadcasts the 8 kept-bits; all lanes do branchless masked
//     ORs into supp (owner's re-OR is idempotent)
// Waves 1-3 stage tile t+1 (ulonglong2) while wave 0 scans tile t.
// Chunks never straddle a 64-row word boundary (96 mod 8 = 0, 8 | 64).
// ---------------------------------------------------------------------------
__global__ __launch_bounds__(256) void nms_scan_k(Ws* __restrict__ ws) {
    __shared__ __align__(16) u64 sbuf[2][TROWS * NWORD];
    const int tid = threadIdx.x;
    const int lane = tid & 63;
    const int wave = tid >> 6;
    const int lmod = lane & 31;
    const u64* __restrict__ mask = ws->mask;

    // stage tile 0 (all threads, 16B vector loads)
    {
        const ulonglong2* src = (const ulonglong2*)mask;
        ulonglong2* dst = (ulonglong2*)sbuf[0];
        for (int e = tid; e < TROWS * NWORD / 2; e += 256) dst[e] = src[e];
    }
    __syncthreads();

    u64 supp = 0ull;
    for (int t = 0; t < NTILE; ++t) {
        const int base = t * TROWS;
        const int nb = min(TROWS, K_PRE - base);
        if (wave == 0) {
            const u64* sm = sbuf[t & 1];
            u64 A[CH], B[CH];
#pragma unroll
            for (int b = 0; b < CH; ++b) A[b] = sm[b * NWORD + lmod];
            for (int s = 0; s < nb; s += 2 * CH) {
                const bool hasB = (s + CH) < nb;
                if (hasB) {
#pragma unroll
                    for (int b = 0; b < CH; ++b) B[b] = sm[(s + CH + b) * NWORD + lmod];
                }
                // ---- process chunk A at offset s ----
                {
                    const int w = (base + s) >> 6;
                    const int bofs = (base + s) & 63;
                    u64 keptw = 0ull;
                    if (lane == w) {
                        u64 cur = supp;
#pragma unroll
                        for (int b = 0; b < CH; ++b) {
                            u64 bit = (cur >> (bofs + b)) & 1ull;
                            u64 sel = bit - 1ull;             // ~0 if row kept
                            cur |= A[b] & sel;
                            keptw |= sel & (1ull << b);
                        }
                        supp = cur;
                    }
                    u64 kb = __shfl(keptw, w);
#pragma unroll
                    for (int b = 0; b < CH; ++b) {
                        u64 sel = 0ull - ((kb >> b) & 1ull);
                        supp |= A[b] & sel;                   // idempotent for owner
                    }
                }
                if (hasB) {
                    if (s + 2 * CH < nb) {
#pragma unroll
                        for (int b = 0; b < CH; ++b)
                            A[b] = sm[(s + 2 * CH + b) * NWORD + lmod];
                    }
                    // ---- process chunk B at offset s+CH ----
                    const int w = (base + s + CH) >> 6;
                    const int bofs = (base + s + CH) & 63;
                    u64 keptw = 0ull;
                    if (lane == w) {
                        u64 cur = supp;
#pragma unroll
                        for (int b = 0; b < CH; ++b) {
                            u64 bit = (cur >> (bofs + b)) & 1ull;
                            u64 sel = bit - 1ull;
                            cur |= B[b] & sel;
                            keptw |= sel & (1ull << b);
                        }
                        supp = cur;
                    }
                    u64 kb = __shfl(keptw, w);
#pragma unroll
                    for (int b = 0; b < CH; ++b) {
                        u64 sel = 0ull - ((kb >> b) & 1ull);
                        supp |= B[b] & sel;
                    }
                }
            }
        } else if (t + 1 < NTILE) {
            const int nbase = (t + 1) * TROWS;
            const int npairs = (min(TROWS, K_PRE - nbase) * NWORD) / 2;
            const ulonglong2* src = (const ulonglong2*)(mask + (size_t)nbase * NWORD);
            ulonglong2* dst = (ulonglong2*)sbuf[(t + 1) & 1];
            for (int e = tid - 64; e < npairs; e += 192) dst[e] = src[e];
        }
        __syncthreads();
    }

    if (wave == 0) {
        // ---- compaction: kept = ~supp (valid words: lanes 0..31 only) ----
        u64 valid;
        if (lane < NWORD - 1)       valid = ~0ull;
        else if (lane == NWORD - 1) valid = (1ull << (K_PRE - (NWORD - 1) * 64)) - 1ull;
        else                        valid = 0ull;
        u64 keepw = (~supp) & valid;
        int cnt = __popcll(keepw);
        int incl = cnt;
        for (int off = 1; off < 64; off <<= 1) {
            int t = __shfl_up(incl, off);
            if (lane >= off) incl += t;
        }
        int pos = incl - cnt;
        u64 kw = keepw;
        while (kw) {
            int b = __ffsll((unsigned long long)kw) - 1;
            kw &= kw - 1ull;
            if (pos < K_POST) ws->rows[pos] = lane * 64 + b;
            ++pos;
        }
        int total = __shfl(incl, 63);
        if (lane == 0) ws->nk = total;
        int start = total < K_POST ? total : K_POST;
        for (int r = start + lane; r < K_POST; r += 64) ws->rows[r] = -1;
    }
}

// ---------------------------------------------------------------------------
// Kernel 6: ROIAlign. grid = (49, 512), block = 256: one output element per
// thread (coalesced stores). Invalid rows -> exact zeros.
// ---------------------------------------------------------------------------
__global__ __launch_bounds__(256) void roi_k(const float* __restrict__ feat,
                                             const Ws* __restrict__ ws,
                                             float* __restrict__ out) {
    const int b = blockIdx.y;
    const int o = blockIdx.x * 256 + threadIdx.x;   // 0..12543
    float* orow = out + (size_t)b * (FC * 49);
    const int row = ws->rows[b];
    if (row < 0) { orow[o] = 0.0f; return; }
    const float4 bx = ws->cand[row];
    const float x1 = bx.x * SCALE, y1 = bx.y * SCALE;
    const float x2 = bx.z * SCALE, y2 = bx.w * SCALE;
    const float rw = fmaxf(x2 - x1, 1.0f);
    const float rh = fmaxf(y2 - y1, 1.0f);
    const float stepx = rw / 14.0f;
    const float stepy = rh / 14.0f;
    const int c = o / 49;
    const int p = o % 49;
    const int oy = p / 7, ox = p % 7;
    const float* fc = feat + (size_t)c * (FH * FW);
    float acc = 0.0f;
    for (int sy = 0; sy < 2; ++sy) {
        float yy = y1 + ((float)(2 * oy + sy) + 0.5f) * stepy;
        float y = fminf(fmaxf(yy, 0.0f), (float)(FH - 1));
        float fy0 = floorf(y);
        int iy0 = (int)fy0;
        int iy1 = min(iy0 + 1, FH - 1);
        float ly = y - fy0;
        for (int sx = 0; sx < 2; ++sx) {
            float xx = x1 + ((float)(2 * ox + sx) + 0.5f) * stepx;
            float x = fminf(fmaxf(xx, 0.0f), (float)(FW - 1));
            float fx0 = floorf(x);
            int ix0 = (int)fx0;
            int ix1 = min(ix0 + 1, FW - 1);
            float lx = x - fx0;
            float v00 = fc[iy0 * FW + ix0];
            float v01 = fc[iy0 * FW + ix1];
            float v10 = fc[iy1 * FW + ix0];
            float v11 = fc[iy1 * FW + ix1];
            acc += v00 * (1.0f - ly) * (1.0f - lx)
                 + v01 * (1.0f - ly) * lx
                 + v10 * ly * (1.0f - lx)
                 + v11 * ly * lx;
        }
    }
    orow[o] = acc * 0.25f;
}

extern "C" void kernel_launch(void* const* d_in, const int* in_sizes, int n_in,
                              void* d_out, int out_size, void* d_ws, size_t ws_size,
                              hipStream_t stream) {
    const float* feature    = (const float*)d_in[0];
    const float* objectness = (const float*)d_in[1];
    const float* deltas     = (const float*)d_in[2];
    const float* anchors    = (const float*)d_in[3];
    Ws* ws = (Ws*)d_ws;
    uint32_t* hist = (uint32_t*)ws->mask;   // alias: hist lives in (pre-)mask space
    float* out = (float*)d_out;

    hipLaunchKernelGGL(zero_k, dim3(1), dim3(1024), 0, stream, ws);
    hipLaunchKernelGGL(hist_k, dim3(256), dim3(256), 0, stream, objectness, hist);
    hipLaunchKernelGGL(resolve_k, dim3(1), dim3(1024), 0, stream, hist, ws);
    hipLaunchKernelGGL(gather_k, dim3((N_ANCH + 255) / 256), dim3(256), 0, stream,
                       objectness, ws);
    hipLaunchKernelGGL(sort_decode_k, dim3(1), dim3(1024), 0, stream, deltas, anchors, ws);
    hipLaunchKernelGGL(nms_mask_k, dim3(K_PRE), dim3(256), 0, stream, ws);
    hipLaunchKernelGGL(nms_scan_k, dim3(1), dim3(256), 0, stream, ws);
    hipLaunchKernelGGL(roi_k, dim3(49, 512), dim3(256), 0, stream, feature, ws, out);
}